// Round 7
// baseline (167.019 us; speedup 1.0000x reference)
//
#include <hip/hip_runtime.h>
#include <cstdint>
#include <cstddef>
#include <utility>

#define HH 256
#define WW 256
#define CIN 16
#define COUT 32
#define NB 2
#define TW 32
#define TH 8
#define HALO 5
#define LR_ROWS (TH + 2*HALO)   // 18
#define LR_COLS (TW + 2*HALO)   // 42
#define NCELL (LR_ROWS*LR_COLS) // 756
#define HW (HH*WW)

// ---------------- compile-time offset tables ----------------
struct Tables {
  int16_t coff[256];    // (g*16+n) -> cell offset dx*LR_COLS+dy (phase 2)
  int16_t pcoff[128];   // dedup'd distinct-pair cell offsets
  uint8_t gmap[256];    // (g*16+n) -> dedup index (phase-1 tree wiring)
  int np;
};

// numpy round-half-to-even for non-negative v (only .0/.5 cases occur)
constexpr int rhe(double v) {
  int f = (int)v;
  double fr = v - (double)f;
  if (fr > 0.5) return f + 1;
  if (fr < 0.5) return f;
  return (f & 1) ? f + 1 : f;
}

constexpr Tables make_tables() {
  Tables t{};
  t.np = 0;
  for (int g = 0; g < 16; ++g) {
    int hp = (g >> 2) + 2;   // rb + gh
    int wp = (g & 3) + 2;    // rb + gw
    int TD[5] = {}, LRr[3] = {};
    for (int j = 0; j < 5; ++j) TD[j] = rhe(j * wp / 2.0) - wp;
    for (int j = 0; j < 3; ++j) LRr[j] = rhe((j + 1) * hp / 2.0) - hp;
    int dxs[16] = {}, dys[16] = {};
    for (int j = 0; j < 5; ++j) { dxs[j]      = -hp;    dys[j]      = TD[j]; }
    for (int j = 0; j < 3; ++j) { dxs[5 + j]  = LRr[j]; dys[5 + j]  =  wp;   }
    for (int j = 0; j < 5; ++j) { dxs[8 + j]  =  hp;    dys[8 + j]  = TD[j]; }
    for (int j = 0; j < 3; ++j) { dxs[13 + j] = LRr[j]; dys[13 + j] = -wp;   }
    for (int n = 0; n < 16; ++n) {
      int co = dxs[n] * LR_COLS + dys[n];
      t.coff[g * 16 + n] = (int16_t)co;
      int d = -1;
      for (int k = 0; k < t.np; ++k)
        if ((int)t.pcoff[k] == co) { d = k; break; }
      if (d < 0) { d = t.np; t.np++; t.pcoff[d] = (int16_t)co; }
      t.gmap[g * 16 + n] = (uint8_t)d;
    }
  }
  return t;
}

constexpr Tables CT = make_tables();
constexpr int NP = CT.np;
static_assert(NP <= 128, "pair table overflow");
__device__ const Tables DT = make_tables();   // for runtime-indexed phase-2 reads

// ---------------- exact transcription of numpy's SIMD f32 exp ----------------
__device__ __forceinline__ float numpy_expf(float v) {
  const float MAGIC = 12582912.0f;                 // 1.5 * 2^23
  float q = fmaf(v, 1.442695040888963407359e+00f, MAGIC);
  q = q - MAGIC;                                   // rint(v*log2e), single rounding
  float r = fmaf(q, -6.93145752e-1f, v);           // Cody-Waite high
  r = fmaf(q, -1.42860677e-6f, r);                 // Cody-Waite low
  float num = fmaf(5.082762527590693718096e-04f, r, 6.757896990527504603057e-03f);
  num = fmaf(num, r, 5.114512081637298353406e-02f);
  num = fmaf(num, r, 2.473615434895520810817e-01f);
  num = fmaf(num, r, 7.257664613233124478488e-01f);
  num = fmaf(num, r, 9.999999999980870924916e-01f);
  float den = fmaf(2.159509375685829852307e-02f, r, -2.742335390411667452936e-01f);
  den = fmaf(den, r, 1.0f);
  float poly = num / den;                          // IEEE f32 division
  return ldexpf(poly, (int)q);                     // exact pow2 scale
}

// ---- phase-1a unit: one distinct-pair sigmoid, compile-time cell offset ----
template<int D>
__device__ __forceinline__ float pair_sig(const float4* xt4, int lbase,
    float4 xc0, float4 xc1, float4 xc2, float4 xc3)
{
#pragma clang fp contract(off)
  constexpr int co = (int)CT.pcoff[D];
  const int cell = lbase + co;
  float4 r0 = xt4[0 * NCELL + cell];
  float4 r1 = xt4[1 * NCELL + cell];
  float4 r2 = xt4[2 * NCELL + cell];
  float4 r3 = xt4[3 * NCELL + cell];
  // sequential channel sum c=0..15 (numpy outer-axis reduce), unfused
  float s = r0.x * xc0.x;
  s += r0.y * xc0.y; s += r0.z * xc0.z; s += r0.w * xc0.w;
  s += r1.x * xc1.x; s += r1.y * xc1.y; s += r1.z * xc1.z; s += r1.w * xc1.w;
  s += r2.x * xc2.x; s += r2.y * xc2.y; s += r2.z * xc2.z; s += r2.w * xc2.w;
  s += r3.x * xc3.x; s += r3.y * xc3.y; s += r3.z * xc3.z; s += r3.w * xc3.w;
  float m = s / 16.0f;                       // exact (pow2)
  float e = numpy_expf(-m);                  // numpy's exact SIMD exp
  float d1 = 1.0f + e;
  return 1.0f / d1;                          // IEEE f32 div
}

template<size_t... D>
__device__ __forceinline__ void pairs_all(float* sgv, std::index_sequence<D...>,
    const float4* xt4, int lbase, float4 xc0, float4 xc1, float4 xc2, float4 xc3)
{
  ((sgv[D] = pair_sig<(int)D>(xt4, lbase, xc0, xc1, xc2, xc3)), ...);
}

// ---- phase-1b unit: numpy SSE2 pairwise tree, compile-time sgv indices ----
template<int G>
__device__ __forceinline__ float group_sim(const float* sgv)
{
#pragma clang fp contract(off)
  float A0 = (sgv[(int)CT.gmap[G*16+0]]  + sgv[(int)CT.gmap[G*16+8]])
           + (sgv[(int)CT.gmap[G*16+4]]  + sgv[(int)CT.gmap[G*16+12]]);
  float A1 = (sgv[(int)CT.gmap[G*16+1]]  + sgv[(int)CT.gmap[G*16+9]])
           + (sgv[(int)CT.gmap[G*16+5]]  + sgv[(int)CT.gmap[G*16+13]]);
  float A2 = (sgv[(int)CT.gmap[G*16+2]]  + sgv[(int)CT.gmap[G*16+10]])
           + (sgv[(int)CT.gmap[G*16+6]]  + sgv[(int)CT.gmap[G*16+14]]);
  float A3 = (sgv[(int)CT.gmap[G*16+3]]  + sgv[(int)CT.gmap[G*16+11]])
           + (sgv[(int)CT.gmap[G*16+7]]  + sgv[(int)CT.gmap[G*16+15]]);
  float ssum = (A0 + A2) + (A1 + A3);
  return ssum / 16.0f;                       // exact (pow2)
}

template<size_t... G>
__device__ __forceinline__ void groups_all(float* sim32, const float* sgv,
                                           std::index_sequence<G...>)
{
  ((sim32[G] = group_sim<(int)G>(sgv)), ...);
}

// ---------------- weight transpose: w[o][c][n] -> wt[n][o][c] ----------------
__global__ void transpose_w(const float* __restrict__ w, float* __restrict__ wt) {
  int i = blockIdx.x * 256 + threadIdx.x;
  if (i < COUT * CIN * 16) {
    int o = i >> 8, c = (i >> 4) & 15, n = i & 15;
    wt[n * (COUT * CIN) + o * CIN + c] = w[i];
  }
}

// ---------------- fused main kernel ----------------
__global__ __launch_bounds__(TW * TH, 2) void adapkc_main(
    const float* __restrict__ x, const float* __restrict__ wt,
    const float* __restrict__ bias, float* __restrict__ out)
{
#pragma clang fp contract(off)   // numpy never fuses mul+add; keep every rounding
  __shared__ float4 xt4[4 * NCELL];

  const int tx = threadIdx.x, ty = threadIdx.y;
  const int tid = ty * TW + tx;
  const int b = blockIdx.z;
  const int h0 = blockIdx.y * TH, w0 = blockIdx.x * TW;

  // ---- stage x tile (+halo 5, zero-padded) ----
  for (int i = tid; i < NCELL; i += TW * TH) {
    int r = i / LR_COLS, cc = i - r * LR_COLS;
    int gh = h0 - HALO + r, gw = w0 - HALO + cc;
    bool ok = (gh >= 0) & (gh < HH) & (gw >= 0) & (gw < WW);
    const float* xp = x + (size_t)b * (CIN * HW) + gh * WW + gw;
#pragma unroll
    for (int q = 0; q < 4; ++q) {
      float4 v = make_float4(0.f, 0.f, 0.f, 0.f);
      if (ok) {
        v.x = xp[(q * 4 + 0) * HW];
        v.y = xp[(q * 4 + 1) * HW];
        v.z = xp[(q * 4 + 2) * HW];
        v.w = xp[(q * 4 + 3) * HW];
      }
      xt4[q * NCELL + i] = v;
    }
  }
  __syncthreads();

  const int lbase = (ty + HALO) * LR_COLS + (tx + HALO);
  const float4 xc0 = xt4[0 * NCELL + lbase];
  const float4 xc1 = xt4[1 * NCELL + lbase];
  const float4 xc2 = xt4[2 * NCELL + lbase];
  const float4 xc3 = xt4[3 * NCELL + lbase];

  // ---- phase 1a: 112 dedup'd pair sigmoids, all indices compile-time ----
  float sgv[NP];
  pairs_all(sgv, std::make_index_sequence<NP>{}, xt4, lbase, xc0, xc1, xc2, xc3);

  // ---- phase 1b: per-group numpy pairwise tree, compile-time wiring ----
  float sim32[16];
  groups_all(sim32, sgv, std::make_index_sequence<16>{});

  // ---- selection: stable ascending sort network + first-argmax of diffs (f32) ----
  float s16[16]; int od[16];
#pragma unroll
  for (int i = 0; i < 16; ++i) { s16[i] = sim32[i]; od[i] = i; }
#pragma unroll
  for (int p = 0; p < 15; ++p) {
#pragma unroll
    for (int j = 0; j < 15 - p; ++j) {
      float a = s16[j], c = s16[j + 1];
      int oa = od[j], oc = od[j + 1];
      bool sw = a > c;                     // strict -> stable
      s16[j] = sw ? c : a; s16[j + 1] = sw ? a : c;
      od[j] = sw ? oc : oa; od[j + 1] = sw ? oa : oc;
    }
  }
  float best = s16[1] - s16[0]; int ori = od[0];
#pragma unroll
  for (int i = 1; i < 15; ++i) {
    float dd = s16[i + 1] - s16[i];
    if (dd > best) { best = dd; ori = od[i]; }   // strict -> first max
  }
  if (!(best >= 0.001f)) ori = 0;                // INIT_INDEX

  // ---- phase 2: out[o] = bias[o] + sum_{c,n} w[o,c,n]*(xc[c] - xr[c,n]) ----
  float acc[COUT];
#pragma unroll
  for (int o = 0; o < COUT; ++o) acc[o] = bias[o];

  for (int n = 0; n < 16; ++n) {
    int cell = lbase + (int)DT.coff[ori * 16 + n];
    float4 r0 = xt4[0 * NCELL + cell];
    float4 r1 = xt4[1 * NCELL + cell];
    float4 r2 = xt4[2 * NCELL + cell];
    float4 r3 = xt4[3 * NCELL + cell];
    float4 p0, p1, p2, p3;
    p0.x = xc0.x - r0.x; p0.y = xc0.y - r0.y; p0.z = xc0.z - r0.z; p0.w = xc0.w - r0.w;
    p1.x = xc1.x - r1.x; p1.y = xc1.y - r1.y; p1.z = xc1.z - r1.z; p1.w = xc1.w - r1.w;
    p2.x = xc2.x - r2.x; p2.y = xc2.y - r2.y; p2.z = xc2.z - r2.z; p2.w = xc2.w - r2.w;
    p3.x = xc3.x - r3.x; p3.y = xc3.y - r3.y; p3.z = xc3.z - r3.z; p3.w = xc3.w - r3.w;
    const float* wn = wt + (n << 9);       // wt[n][o][c], uniform address
#pragma unroll
    for (int o = 0; o < COUT; ++o) {
      const float4* wv = (const float4*)(wn + (o << 4));
      float4 w0 = wv[0], w1 = wv[1], w2 = wv[2], w3 = wv[3];
      float a = acc[o];
      a = fmaf(w0.x, p0.x, a); a = fmaf(w0.y, p0.y, a);
      a = fmaf(w0.z, p0.z, a); a = fmaf(w0.w, p0.w, a);
      a = fmaf(w1.x, p1.x, a); a = fmaf(w1.y, p1.y, a);
      a = fmaf(w1.z, p1.z, a); a = fmaf(w1.w, p1.w, a);
      a = fmaf(w2.x, p2.x, a); a = fmaf(w2.y, p2.y, a);
      a = fmaf(w2.z, p2.z, a); a = fmaf(w2.w, p2.w, a);
      a = fmaf(w3.x, p3.x, a); a = fmaf(w3.y, p3.y, a);
      a = fmaf(w3.z, p3.z, a); a = fmaf(w3.w, p3.w, a);
      acc[o] = a;
    }
  }

  const int hh = h0 + ty, wcol = w0 + tx;
  float* op = out + (size_t)b * (COUT * HW) + hh * WW + wcol;
#pragma unroll
  for (int o = 0; o < COUT; ++o) op[o * HW] = acc[o];
}

extern "C" void kernel_launch(void* const* d_in, const int* in_sizes, int n_in,
                              void* d_out, int out_size, void* d_ws, size_t ws_size,
                              hipStream_t stream) {
  const float* x    = (const float*)d_in[0];
  const float* w    = (const float*)d_in[1];
  const float* bias = (const float*)d_in[2];
  float* out = (float*)d_out;
  float* wt  = (float*)d_ws;   // 16*32*16 f32 = 32 KB scratch

  hipLaunchKernelGGL(transpose_w, dim3(32), dim3(256), 0, stream, w, wt);

  dim3 grid(WW / TW, HH / TH, NB);
  dim3 block(TW, TH, 1);
  hipLaunchKernelGGL(adapkc_main, grid, block, 0, stream, x, wt, bias, out);
}

// Round 8
// 101.530 us; speedup vs baseline: 1.6450x; 1.6450x over previous
//
#include <hip/hip_runtime.h>
#include <cstdint>
#include <cstddef>

#define HH 256
#define WW 256
#define CIN 16
#define COUT 32
#define NB 2
#define TW 32
#define TH 8
#define HALO 5
#define LR_ROWS (TH + 2*HALO)   // 18
#define LR_COLS (TW + 2*HALO)   // 42
#define NCELL (LR_ROWS*LR_COLS) // 756
#define HW (HH*WW)

// ---------------- compile-time offset tables ----------------
struct alignas(16) Tables {
  int16_t coff[256];    // (g*16+n) -> cell offset dx*LR_COLS+dy (phase 2)
  int16_t pcoff[128];   // dedup'd distinct-pair cell offsets
  uint8_t gmap[256];    // (g*16+n) -> dedup index (phase-1 tree wiring)
  int np;
};

// numpy round-half-to-even for non-negative v (only .0/.5 cases occur)
constexpr int rhe(double v) {
  int f = (int)v;
  double fr = v - (double)f;
  if (fr > 0.5) return f + 1;
  if (fr < 0.5) return f;
  return (f & 1) ? f + 1 : f;
}

constexpr Tables make_tables() {
  Tables t{};
  t.np = 0;
  for (int g = 0; g < 16; ++g) {
    int hp = (g >> 2) + 2;   // rb + gh
    int wp = (g & 3) + 2;    // rb + gw
    int TD[5] = {}, LRr[3] = {};
    for (int j = 0; j < 5; ++j) TD[j] = rhe(j * wp / 2.0) - wp;
    for (int j = 0; j < 3; ++j) LRr[j] = rhe((j + 1) * hp / 2.0) - hp;
    int dxs[16] = {}, dys[16] = {};
    for (int j = 0; j < 5; ++j) { dxs[j]      = -hp;    dys[j]      = TD[j]; }
    for (int j = 0; j < 3; ++j) { dxs[5 + j]  = LRr[j]; dys[5 + j]  =  wp;   }
    for (int j = 0; j < 5; ++j) { dxs[8 + j]  =  hp;    dys[8 + j]  = TD[j]; }
    for (int j = 0; j < 3; ++j) { dxs[13 + j] = LRr[j]; dys[13 + j] = -wp;   }
    for (int n = 0; n < 16; ++n) {
      int co = dxs[n] * LR_COLS + dys[n];
      t.coff[g * 16 + n] = (int16_t)co;
      int d = -1;
      for (int k = 0; k < t.np; ++k)
        if ((int)t.pcoff[k] == co) { d = k; break; }
      if (d < 0) { d = t.np; t.np++; t.pcoff[d] = (int16_t)co; }
      t.gmap[g * 16 + n] = (uint8_t)d;
    }
  }
  return t;
}

constexpr Tables CT = make_tables();
constexpr int NP = CT.np;
static_assert(NP <= 128, "pair table overflow");
static_assert(NP % 4 == 0, "batch remainder");
__device__ const Tables DT = make_tables();   // for runtime-indexed phase-2 reads

// ---------------- exact transcription of numpy's SIMD f32 exp ----------------
__device__ __forceinline__ float numpy_expf(float v) {
  const float MAGIC = 12582912.0f;                 // 1.5 * 2^23
  float q = fmaf(v, 1.442695040888963407359e+00f, MAGIC);
  q = q - MAGIC;                                   // rint(v*log2e), single rounding
  float r = fmaf(q, -6.93145752e-1f, v);           // Cody-Waite high
  r = fmaf(q, -1.42860677e-6f, r);                 // Cody-Waite low
  float num = fmaf(5.082762527590693718096e-04f, r, 6.757896990527504603057e-03f);
  num = fmaf(num, r, 5.114512081637298353406e-02f);
  num = fmaf(num, r, 2.473615434895520810817e-01f);
  num = fmaf(num, r, 7.257664613233124478488e-01f);
  num = fmaf(num, r, 9.999999999980870924916e-01f);
  float den = fmaf(2.159509375685829852307e-02f, r, -2.742335390411667452936e-01f);
  den = fmaf(den, r, 1.0f);
  float poly = num / den;                          // IEEE f32 division
  return ldexpf(poly, (int)q);                     // exact pow2 scale
}

// ---------------- weight transpose: w[o][c][n] -> wt[n][o][c] ----------------
__global__ void transpose_w(const float* __restrict__ w, float* __restrict__ wt) {
  int i = blockIdx.x * 256 + threadIdx.x;
  if (i < COUT * CIN * 16) {
    int o = i >> 8, c = (i >> 4) & 15, n = i & 15;
    wt[n * (COUT * CIN) + o * CIN + c] = w[i];
  }
}

// ---------------- fused main kernel ----------------
__global__ __launch_bounds__(TW * TH)
__attribute__((amdgpu_waves_per_eu(2, 2)))   // grid caps us at 2 waves/EU anyway:
void adapkc_main(                            // free the scheduler to use VGPRs for ILP
    const float* __restrict__ x, const float* __restrict__ wt,
    const float* __restrict__ bias, float* __restrict__ out)
{
#pragma clang fp contract(off)   // numpy never fuses mul+add; keep every rounding
  __shared__ float4 xt4[4 * NCELL];

  const int tx = threadIdx.x, ty = threadIdx.y;
  const int tid = ty * TW + tx;
  const int b = blockIdx.z;
  const int h0 = blockIdx.y * TH, w0 = blockIdx.x * TW;

  // ---- stage x tile (+halo 5, zero-padded) ----
  for (int i = tid; i < NCELL; i += TW * TH) {
    int r = i / LR_COLS, cc = i - r * LR_COLS;
    int gh = h0 - HALO + r, gw = w0 - HALO + cc;
    bool ok = (gh >= 0) & (gh < HH) & (gw >= 0) & (gw < WW);
    const float* xp = x + (size_t)b * (CIN * HW) + gh * WW + gw;
#pragma unroll
    for (int q = 0; q < 4; ++q) {
      float4 v = make_float4(0.f, 0.f, 0.f, 0.f);
      if (ok) {
        v.x = xp[(q * 4 + 0) * HW];
        v.y = xp[(q * 4 + 1) * HW];
        v.z = xp[(q * 4 + 2) * HW];
        v.w = xp[(q * 4 + 3) * HW];
      }
      xt4[q * NCELL + i] = v;
    }
  }
  __syncthreads();

  const int lbase = (ty + HALO) * LR_COLS + (tx + HALO);
  const float4 xc0 = xt4[0 * NCELL + lbase];
  const float4 xc1 = xt4[1 * NCELL + lbase];
  const float4 xc2 = xt4[2 * NCELL + lbase];
  const float4 xc3 = xt4[3 * NCELL + lbase];

  // ---- phase 1a: dedup'd pair sigmoids, batched 4-wide for MLP ----
  float sgv[NP];
#pragma unroll
  for (int bb = 0; bb < NP / 4; ++bb) {
    float4 R[4][4];
#pragma unroll
    for (int j = 0; j < 4; ++j) {
      const int cell = lbase + (int)CT.pcoff[bb * 4 + j];
#pragma unroll
      for (int q = 0; q < 4; ++q) R[j][q] = xt4[q * NCELL + cell];
    }
#pragma unroll
    for (int j = 0; j < 4; ++j) {
      // sequential channel sum c=0..15 (numpy outer-axis reduce), unfused
      float s = R[j][0].x * xc0.x;
      s += R[j][0].y * xc0.y; s += R[j][0].z * xc0.z; s += R[j][0].w * xc0.w;
      s += R[j][1].x * xc1.x; s += R[j][1].y * xc1.y;
      s += R[j][1].z * xc1.z; s += R[j][1].w * xc1.w;
      s += R[j][2].x * xc2.x; s += R[j][2].y * xc2.y;
      s += R[j][2].z * xc2.z; s += R[j][2].w * xc2.w;
      s += R[j][3].x * xc3.x; s += R[j][3].y * xc3.y;
      s += R[j][3].z * xc3.z; s += R[j][3].w * xc3.w;
      float m = s / 16.0f;                       // exact (pow2)
      float e = numpy_expf(-m);                  // numpy's exact SIMD exp
      float d1 = 1.0f + e;
      sgv[bb * 4 + j] = 1.0f / d1;               // IEEE f32 div
    }
  }

  // ---- phase 1b: per-group numpy SSE2 pairwise tree (compile-time wiring) ----
  float sim32[16];
#pragma unroll
  for (int g = 0; g < 16; ++g) {
    float A0 = (sgv[CT.gmap[g*16+0]]  + sgv[CT.gmap[g*16+8]])
             + (sgv[CT.gmap[g*16+4]]  + sgv[CT.gmap[g*16+12]]);
    float A1 = (sgv[CT.gmap[g*16+1]]  + sgv[CT.gmap[g*16+9]])
             + (sgv[CT.gmap[g*16+5]]  + sgv[CT.gmap[g*16+13]]);
    float A2 = (sgv[CT.gmap[g*16+2]]  + sgv[CT.gmap[g*16+10]])
             + (sgv[CT.gmap[g*16+6]]  + sgv[CT.gmap[g*16+14]]);
    float A3 = (sgv[CT.gmap[g*16+3]]  + sgv[CT.gmap[g*16+11]])
             + (sgv[CT.gmap[g*16+7]]  + sgv[CT.gmap[g*16+15]]);
    float ssum = (A0 + A2) + (A1 + A3);
    sim32[g] = ssum / 16.0f;                     // exact (pow2)
  }

  // ---- selection: stable ascending sort network + first-argmax of diffs (f32) ----
  float s16[16]; int od[16];
#pragma unroll
  for (int i = 0; i < 16; ++i) { s16[i] = sim32[i]; od[i] = i; }
#pragma unroll
  for (int p = 0; p < 15; ++p) {
#pragma unroll
    for (int j = 0; j < 15 - p; ++j) {
      float a = s16[j], c = s16[j + 1];
      int oa = od[j], oc = od[j + 1];
      bool sw = a > c;                     // strict -> stable
      s16[j] = sw ? c : a; s16[j + 1] = sw ? a : c;
      od[j] = sw ? oc : oa; od[j + 1] = sw ? oa : oc;
    }
  }
  float best = s16[1] - s16[0]; int ori = od[0];
#pragma unroll
  for (int i = 1; i < 15; ++i) {
    float dd = s16[i + 1] - s16[i];
    if (dd > best) { best = dd; ori = od[i]; }   // strict -> first max
  }
  if (!(best >= 0.001f)) ori = 0;                // INIT_INDEX

  // ---- phase 2: out[o] = bias[o] + sum_{c,n} w[o,c,n]*(xc[c] - xr[c,n]) ----
  // prefetch the selected offset row (16 x int16 = 32 B) as 2 vector loads
  const int4* crow = (const int4*)&DT.coff[ori * 16];
  int4 cw0 = crow[0], cw1 = crow[1];
  int cellv[16];
  {
    int ws[8] = {cw0.x, cw0.y, cw0.z, cw0.w, cw1.x, cw1.y, cw1.z, cw1.w};
#pragma unroll
    for (int k = 0; k < 8; ++k) {
      cellv[2*k]   = lbase + (int)(int16_t)(ws[k] & 0xffff);
      cellv[2*k+1] = lbase + (int)(int16_t)((unsigned)ws[k] >> 16);
    }
  }

  float acc[COUT];
#pragma unroll
  for (int o = 0; o < COUT; ++o) acc[o] = bias[o];

#pragma unroll
  for (int n = 0; n < 16; ++n) {
    int cell = cellv[n];
    float4 r0 = xt4[0 * NCELL + cell];
    float4 r1 = xt4[1 * NCELL + cell];
    float4 r2 = xt4[2 * NCELL + cell];
    float4 r3 = xt4[3 * NCELL + cell];
    float4 p0, p1, p2, p3;
    p0.x = xc0.x - r0.x; p0.y = xc0.y - r0.y; p0.z = xc0.z - r0.z; p0.w = xc0.w - r0.w;
    p1.x = xc1.x - r1.x; p1.y = xc1.y - r1.y; p1.z = xc1.z - r1.z; p1.w = xc1.w - r1.w;
    p2.x = xc2.x - r2.x; p2.y = xc2.y - r2.y; p2.z = xc2.z - r2.z; p2.w = xc2.w - r2.w;
    p3.x = xc3.x - r3.x; p3.y = xc3.y - r3.y; p3.z = xc3.z - r3.z; p3.w = xc3.w - r3.w;
    const float* wn = wt + (n << 9);       // wt[n][o][c], uniform address
#pragma unroll
    for (int o = 0; o < COUT; ++o) {
      const float4* wv = (const float4*)(wn + (o << 4));
      float4 w0 = wv[0], w1 = wv[1], w2 = wv[2], w3 = wv[3];
      float a = acc[o];
      a = fmaf(w0.x, p0.x, a); a = fmaf(w0.y, p0.y, a);
      a = fmaf(w0.z, p0.z, a); a = fmaf(w0.w, p0.w, a);
      a = fmaf(w1.x, p1.x, a); a = fmaf(w1.y, p1.y, a);
      a = fmaf(w1.z, p1.z, a); a = fmaf(w1.w, p1.w, a);
      a = fmaf(w2.x, p2.x, a); a = fmaf(w2.y, p2.y, a);
      a = fmaf(w2.z, p2.z, a); a = fmaf(w2.w, p2.w, a);
      a = fmaf(w3.x, p3.x, a); a = fmaf(w3.y, p3.y, a);
      a = fmaf(w3.z, p3.z, a); a = fmaf(w3.w, p3.w, a);
      acc[o] = a;
    }
  }

  const int hh = h0 + ty, wcol = w0 + tx;
  float* op = out + (size_t)b * (COUT * HW) + hh * WW + wcol;
#pragma unroll
  for (int o = 0; o < COUT; ++o) op[o * HW] = acc[o];
}

extern "C" void kernel_launch(void* const* d_in, const int* in_sizes, int n_in,
                              void* d_out, int out_size, void* d_ws, size_t ws_size,
                              hipStream_t stream) {
  const float* x    = (const float*)d_in[0];
  const float* w    = (const float*)d_in[1];
  const float* bias = (const float*)d_in[2];
  float* out = (float*)d_out;
  float* wt  = (float*)d_ws;   // 16*32*16 f32 = 32 KB scratch

  hipLaunchKernelGGL(transpose_w, dim3(32), dim3(256), 0, stream, w, wt);

  dim3 grid(WW / TW, HH / TH, NB);
  dim3 block(TW, TH, 1);
  hipLaunchKernelGGL(adapkc_main, grid, block, 0, stream, x, wt, bias, out);
}